// Round 14
// baseline (266.925 us; speedup 1.0000x reference)
//
#include <hip/hip_runtime.h>
#include <hip/hip_fp16.h>

#define N 4096
#define NITER 100
#define LOG2E 1.44269504088896340736f
#define TOL 2e-3f        // on |q/tot - 1| ~ |dv|; residual -> plan err ~8e-9 << 7e-8 slack
#define NB 256
#define NT 1024
#define ROWS 16                      // rows owned per block; E=exp(Mr) f16 in LDS
#define TILE_BYTES (ROWS * N * 2)    // 128 KiB
#define NEV (1 + 2 * NITER)          // barrier events: e0 + 2/iter

typedef unsigned short u16;

// Cross-XCD-coherent scalar accessors (per-XCD L2 NOT coherent). 32-bit ONLY
// (R7: 64-bit agent atomics regressed). Ordering via release/acquire chains.
__device__ __forceinline__ float aload(const float* p) {
    return __hip_atomic_load(p, __ATOMIC_RELAXED, __HIP_MEMORY_SCOPE_AGENT);
}
__device__ __forceinline__ void astore(float* p, float x) {
    __hip_atomic_store(p, x, __ATOMIC_RELAXED, __HIP_MEMORY_SCOPE_AGENT);
}

__device__ __forceinline__ float fexp2(float x) {
#if __has_builtin(__builtin_amdgcn_exp2f)
    return __builtin_amdgcn_exp2f(x);        // raw v_exp_f32 (setup only now)
#else
    return __expf(x * 0.6931471805599453f);
#endif
}

// f16 pack/unpack via standard hip_fp16 API (R13's _Float16 path broke compile)
__device__ __forceinline__ unsigned pkh2(float a, float b) {
    union { __half2 h; unsigned u; } c;
    c.h = __floats2half2_rn(a, b);
    return c.u;
}
__device__ __forceinline__ float2 uph2(unsigned u) {
    union { __half2 h; unsigned u; } c;
    c.u = u;
    return __half22float2(c.h);
}

// Aggregator barrier with payload. Arrival = ONE release store to an own flag
// slot (no RMW). Block 0 polls all NB flags (acquire; sentinel int -1), max-
// reduces the float payloads, release-stores root[e] whose VALUE carries the
// result. Everyone else spins on the single root address (R10/R11 lesson).
// mode 0: root=1; mode 1: root=bits(max) (>0); mode 2: root= max<TOL ? 2 : 1.
__device__ __forceinline__ int gbar(int e, int payload, int mode,
                                    float* flags, int* roots,
                                    float* sbar, int* shb) {
    const int t = threadIdx.x;
    const int lane = t & 63;
    const int wave = t >> 6;
    __syncthreads();                 // join block + drain its stores
    if (blockIdx.x == 0) {
        float val = -1e30f;
        if (t == 0) {
            val = __int_as_float(payload);
        } else if (t < NB) {
            const int* fi = (const int*)(flags + (size_t)e * NB + t);
            int u = __hip_atomic_load(fi, __ATOMIC_ACQUIRE, __HIP_MEMORY_SCOPE_AGENT);
            while (u == -1) {
                __builtin_amdgcn_s_sleep(1);
                u = __hip_atomic_load(fi, __ATOMIC_ACQUIRE, __HIP_MEMORY_SCOPE_AGENT);
            }
            val = __int_as_float(u);
        }
        if (wave < 4) {
#pragma unroll
            for (int off = 32; off; off >>= 1) val = fmaxf(val, __shfl_down(val, off));
            if (lane == 0) sbar[wave] = val;
        }
        __syncthreads();
        if (t == 0) {
            const float m = fmaxf(fmaxf(sbar[0], sbar[1]), fmaxf(sbar[2], sbar[3]));
            int rv = 1;
            if (mode == 1) rv = __float_as_int(m);
            else if (mode == 2) rv = (m < TOL) ? 2 : 1;
            __hip_atomic_store(&roots[e], rv, __ATOMIC_RELEASE, __HIP_MEMORY_SCOPE_AGENT);
            *shb = rv;
        }
    } else {
        if (t == 0) {
            __hip_atomic_store((int*)(flags + (size_t)e * NB + blockIdx.x), payload,
                               __ATOMIC_RELEASE, __HIP_MEMORY_SCOPE_AGENT);
            int r = __hip_atomic_load(&roots[e], __ATOMIC_ACQUIRE, __HIP_MEMORY_SCOPE_AGENT);
            while (r == 0) {
                __builtin_amdgcn_s_sleep(1);
                r = __hip_atomic_load(&roots[e], __ATOMIC_ACQUIRE, __HIP_MEMORY_SCOPE_AGENT);
            }
            *shb = r;
        }
    }
    __syncthreads();
    return *shb;
}

// Persistent co-resident kernel. All-exp-domain Sinkhorn on E=exp(Mr):
//   eu_r = p_r / sum_j E_rj ev_j ;  ev_j *= q_j / tot_j ;  plan = E*eu*ev.
// NO SOR (R7/R8). E precomputed once (exp leaves the loop entirely).
__global__ __launch_bounds__(NT) void ot_all(const float* __restrict__ p,
                                             const float* __restrict__ q,
                                             const float* __restrict__ C,
                                             int* roots,
                                             float* flags,
                                             float* ev,
                                             float* part,
                                             float* __restrict__ out) {
    extern __shared__ u16 tile[];        // [ROWS][N]: u16 quant, then f16 E in place
    const int t = threadIdx.x;
    const int b = blockIdx.x;
    const int lane = t & 63;
    const int wave = t >> 6;             // 0..15
    const int gid = b * NT + t;
    const int r0 = b * ROWS;             // owned rows
    const int c0 = b * 16;               // owned cols (phase B)
    const int j0 = t * 4;                // per-thread col slice

    __shared__ float sred[4][16];
    __shared__ float wbc[4];
    __shared__ float s2[16][16];
    __shared__ float dm[16];
    __shared__ float sbar[4];
    __shared__ int shb;
    __shared__ float pp[ROWS], qq[16], eu[ROWS];
    __shared__ float sMown;

    // ---------------- phase 0: ev-init + own-rows max; publish early ----------------
    if (gid < N) astore(&ev[gid], 1.0f);
    {
        const float4* Crow = (const float4*)(C + (size_t)r0 * N);
        float m = 0.f;
        for (int i = t; i < ROWS * N / 4; i += NT) {
            float4 c = Crow[i];
            m = fmaxf(m, fmaxf(fmaxf(c.x, c.y), fmaxf(c.z, c.w)));
        }
#pragma unroll
        for (int off = 32; off; off >>= 1) m = fmaxf(m, __shfl_down(m, off));
        if (lane == 0) dm[wave] = m;
        __syncthreads();
        if (t == 0) {
            m = dm[0];
#pragma unroll
            for (int i = 1; i < 16; ++i) m = fmaxf(m, dm[i]);
            sMown = m;
        }
        __syncthreads();                 // drains ev stores + sMown visible
    }
    // non-agg blocks arrive at e0 now (payload = own max); quantization overlaps
    if (b != 0 && t == 0)
        __hip_atomic_store((int*)(flags + b), __float_as_int(sMown),
                           __ATOMIC_RELEASE, __HIP_MEMORY_SCOPE_AGENT);

    // ---------------- phase 1: u16-quantize own rows w/ LOCAL max (overlaps e0) ----------------
    {
        const float qmul = 65535.0f / sMown;
        const float4* Crow = (const float4*)(C + (size_t)r0 * N);
        uint2* T2 = (uint2*)tile;
        for (int i = t; i < ROWS * N / 4; i += NT) {
            float4 a = Crow[i];
            uint2 o;
            o.x = min(65535u, __float2uint_rn(a.x * qmul)) | (min(65535u, __float2uint_rn(a.y * qmul)) << 16);
            o.y = min(65535u, __float2uint_rn(a.z * qmul)) | (min(65535u, __float2uint_rn(a.w * qmul)) << 16);
            T2[i] = o;
        }
        if (t < ROWS) {
            pp[t] = p[r0 + t];
            qq[t] = q[c0 + t];
        }
    }
    __syncthreads();
    // ---- e0 resolve: agg polls+reduces; others spin root (maxC in root value) ----
    if (b == 0) {
        float val = (t == 0) ? sMown : -1e30f;
        if (t > 0 && t < NB) {
            const int* fi = (const int*)(flags + t);
            int u = __hip_atomic_load(fi, __ATOMIC_ACQUIRE, __HIP_MEMORY_SCOPE_AGENT);
            while (u == -1) {
                __builtin_amdgcn_s_sleep(1);
                u = __hip_atomic_load(fi, __ATOMIC_ACQUIRE, __HIP_MEMORY_SCOPE_AGENT);
            }
            val = __int_as_float(u);
        }
        if (wave < 4) {
#pragma unroll
            for (int off = 32; off; off >>= 1) val = fmaxf(val, __shfl_down(val, off));
            if (lane == 0) sbar[wave] = val;
        }
        __syncthreads();
        if (t == 0) {
            const float m = fmaxf(fmaxf(sbar[0], sbar[1]), fmaxf(sbar[2], sbar[3]));
            __hip_atomic_store(&roots[0], __float_as_int(m), __ATOMIC_RELEASE, __HIP_MEMORY_SCOPE_AGENT);
            shb = __float_as_int(m);
        }
    } else {
        if (t == 0) {
            int r = __hip_atomic_load(&roots[0], __ATOMIC_ACQUIRE, __HIP_MEMORY_SCOPE_AGENT);
            while (r == 0) {
                __builtin_amdgcn_s_sleep(1);
                r = __hip_atomic_load(&roots[0], __ATOMIC_ACQUIRE, __HIP_MEMORY_SCOPE_AGENT);
            }
            shb = r;
        }
    }
    __syncthreads();
    const float maxC = __int_as_float(shb);

    // ---------------- convert tile in place: u16 q -> f16 E = exp2(q * nd2) ----------------
    {
        const float nd2 = -(20.0f / 65535.0f) * (sMown / maxC) * LOG2E;
        uint2* T2 = (uint2*)tile;
        for (int i = t; i < ROWS * N / 4; i += NT) {
            uint2 a = T2[i];
            float e0 = fexp2((float)(a.x & 0xffffu) * nd2);
            float e1 = fexp2((float)(a.x >> 16) * nd2);
            float e2 = fexp2((float)(a.y & 0xffffu) * nd2);
            float e3 = fexp2((float)(a.y >> 16) * nd2);
            a.x = pkh2(e0, e1);
            a.y = pkh2(e2, e3);
            T2[i] = a;
        }
    }
    __syncthreads();
    float evreg = 1.0f;    // own col's ev (valid for t<16; only this block writes it)

    // ---------------- Sinkhorn iterations (exp domain, plain Gauss-Seidel) ----------------
    for (int it = 0; it < NITER; ++it) {
        // ---- phase A: S_r = sum_j E_rj*ev_j; eu_r = p_r/S_r; colpart_j += E*ev*eu ----
        float evv[4];
#pragma unroll
        for (int k = 0; k < 4; ++k) evv[k] = aload(&ev[j0 + k]);
        float ca[4] = {0.f, 0.f, 0.f, 0.f};

        for (int ch = 0; ch < 4; ++ch) {
            const int rl = ch * 4;
            float tq[4][4], sp[4];
#pragma unroll
            for (int r = 0; r < 4; ++r) {
                uint2 a = *(const uint2*)(tile + (size_t)(rl + r) * N + j0);
                float2 x0 = uph2(a.x);
                float2 x1 = uph2(a.y);
                float t0 = x0.x * evv[0];
                float t1 = x0.y * evv[1];
                float t2 = x1.x * evv[2];
                float t3 = x1.y * evv[3];
                tq[r][0] = t0; tq[r][1] = t1; tq[r][2] = t2; tq[r][3] = t3;
                sp[r] = (t0 + t1) + (t2 + t3);
            }
#pragma unroll
            for (int r = 0; r < 4; ++r) {
                float s = sp[r];
#pragma unroll
                for (int off = 32; off; off >>= 1) s += __shfl_down(s, off);
                if (lane == 0) sred[r][wave] = s;
            }
            __syncthreads();
            if (wave < 4) {  // wave w finalizes local row rl+w
                float s = (lane < 16) ? sred[wave][lane] : 0.f;
                s += __shfl_down(s, 8);
                s += __shfl_down(s, 4);
                s += __shfl_down(s, 2);
                s += __shfl_down(s, 1);
                if (lane == 0) {
                    const float w = pp[rl + wave] / s;   // eu_r
                    wbc[wave] = w;
                    eu[rl + wave] = w;                   // kept for final
                }
            }
            __syncthreads();
#pragma unroll
            for (int r = 0; r < 4; ++r) {
                const float w = wbc[r];
#pragma unroll
                for (int k = 0; k < 4; ++k) ca[k] = fmaf(tq[r][k], w, ca[k]);
            }
        }
#pragma unroll
        for (int k = 0; k < 4; ++k) astore(&part[(size_t)b * N + j0 + k], ca[k]);
        gbar(1 + 2 * it, __float_as_int(1.0f), 0, flags, roots, sbar, &shb);

        // ---- phase B: tot_j = sum_b part[b][j]; ev_j *= q_j/tot; d = |q/tot - 1| ----
        float dblk = 0.f;
        {
            const int cl = t & 15;
            const int ch = t >> 4;       // 0..63
            const int c = c0 + cl;
            float s = 0.f;
#pragma unroll
            for (int k = 0; k < 4; ++k) s += aload(&part[(size_t)(ch + 64 * k) * N + c]);
            s += __shfl_down(s, 16);
            s += __shfl_down(s, 32);
            if (lane < 16) s2[cl][wave] = s;
            __syncthreads();
            if (t < 16) {
                float tot = 0.f;
#pragma unroll
                for (int w = 0; w < 16; ++w) tot += s2[t][w];
                const float rr = qq[t] / tot;
                const float evn = evreg * rr;
                astore(&ev[c0 + t], evn);
                evreg = evn;
                float d = fabsf(rr - 1.0f);
                d = fmaxf(d, __shfl_down(d, 8));
                d = fmaxf(d, __shfl_down(d, 4));
                d = fmaxf(d, __shfl_down(d, 2));
                d = fmaxf(d, __shfl_down(d, 1));
                dblk = d;                // valid on t==0
            }
        }
        const int rv = gbar(2 + 2 * it, __float_as_int(dblk), 2, flags, roots, sbar, &shb);
        if (rv == 2) break;              // single-source decision: uniform by construction
    }

    // ---------------- final: out = E * eu_r * ev_j (no exp) ----------------
    {
        float ev4[4];
#pragma unroll
        for (int k = 0; k < 4; ++k) ev4[k] = aload(&ev[j0 + k]);
#pragma unroll 4
        for (int r = 0; r < ROWS; ++r) {
            const float g = eu[r];
            uint2 a = *(const uint2*)(tile + (size_t)r * N + j0);
            float2 x0 = uph2(a.x);
            float2 x1 = uph2(a.y);
            float4 o;
            o.x = x0.x * (g * ev4[0]);
            o.y = x0.y * (g * ev4[1]);
            o.z = x1.x * (g * ev4[2]);
            o.w = x1.y * (g * ev4[3]);
            *(float4*)(out + (size_t)(r0 + r) * N + j0) = o;
        }
    }
}

extern "C" void kernel_launch(void* const* d_in, const int* in_sizes, int n_in,
                              void* d_out, int out_size, void* d_ws, size_t ws_size,
                              hipStream_t stream) {
    const float* p = (const float*)d_in[0];
    const float* q = (const float*)d_in[1];
    const float* C = (const float*)d_in[2];
    float* out = (float*)d_out;

    char* base = (char*)d_ws;
    int* roots = (int*)base;                            // NEV ints, memset 0
    float* flags = (float*)(base + 4096);               // NEV*NB floats, memset 0xFF (sentinel -1)
    float* ev = (float*)(base + 216 * 1024);            // N floats (init'd in-kernel)
    float* part = (float*)(base + 256 * 1024);          // NB x N f32 = 4 MB (barrier-guarded)

    (void)hipMemsetAsync(base, 0, 4096, stream);                                        // roots
    (void)hipMemsetAsync(base + 4096, 0xFF, (size_t)NEV * NB * sizeof(float), stream);  // flag sentinels

    (void)hipFuncSetAttribute((const void*)ot_all, hipFuncAttributeMaxDynamicSharedMemorySize, TILE_BYTES);

    void* args[] = {(void*)&p, (void*)&q, (void*)&C, (void*)&roots,
                    (void*)&flags, (void*)&ev, (void*)&part, (void*)&out};
    (void)hipLaunchCooperativeKernel((void*)ot_all, dim3(NB), dim3(NT), args, TILE_BYTES, stream);
}

// Round 15
// 236.116 us; speedup vs baseline: 1.1305x; 1.1305x over previous
//
#include <hip/hip_runtime.h>
#include <hip/hip_fp16.h>

#define N 4096
#define NITER 100
#define LOG2E 1.44269504088896340736f
#define TOL 2e-3f        // on |q/tot - 1|; residual -> plan err ~8e-9 << 7e-8 slack
#define NB 256
#define NT 1024
#define ROWS 16                      // rows owned per block; E=exp(Mr) f16 in LDS
#define TILE_BYTES (ROWS * N * 2)    // 128 KiB
#define GRPS 8
#define BPG 32                       // blocks per group
#define EVSTRIDE 144                 // ints per event: 8 grp counters @16-int spacing + root @128

typedef unsigned short u16;

// Cross-XCD-coherent scalar accessors (per-XCD L2 NOT coherent). 32-bit ONLY
// (R7: 64-bit agent atomics regressed). Ordering via the barrier's
// ACQ_REL arrival chain + acquire root spin (R12-proven).
__device__ __forceinline__ float aload(const float* p) {
    return __hip_atomic_load(p, __ATOMIC_RELAXED, __HIP_MEMORY_SCOPE_AGENT);
}
__device__ __forceinline__ void astore(float* p, float x) {
    __hip_atomic_store(p, x, __ATOMIC_RELAXED, __HIP_MEMORY_SCOPE_AGENT);
}

__device__ __forceinline__ float fexp2(float x) {
#if __has_builtin(__builtin_amdgcn_exp2f)
    return __builtin_amdgcn_exp2f(x);        // raw v_exp_f32 (setup only)
#else
    return __expf(x * 0.6931471805599453f);
#endif
}

// f16 pack/unpack via hip_fp16 (R14-proven)
__device__ __forceinline__ unsigned pkh2(float a, float b) {
    union { __half2 h; unsigned u; } c;
    c.h = __floats2half2_rn(a, b);
    return c.u;
}
__device__ __forceinline__ float2 uph2(unsigned u) {
    union { __half2 h; unsigned u; } c;
    c.u = u;
    return __half22float2(c.h);
}

// Hierarchical one-shot barrier (R12-proven, ~4.6us/event). Arrival: acq_rel
// fetch_add on own group's line (8 lines in parallel); group-last acq_rel-adds
// the root. Wait: spin ONE address (root) with acquire + s_sleep (R11/R14
// lessons: no multi-address polling, no aggregator two-hop).
__device__ __forceinline__ void gbar_arrive(int* bar, int e) {   // t==0 only
    int* base = bar + e * EVSTRIDE;
    const int g = (int)(blockIdx.x >> 5);
    int r = __hip_atomic_fetch_add(base + g * 16, 1, __ATOMIC_ACQ_REL, __HIP_MEMORY_SCOPE_AGENT);
    if (r == BPG - 1)
        __hip_atomic_fetch_add(base + 128, 1, __ATOMIC_ACQ_REL, __HIP_MEMORY_SCOPE_AGENT);
}
__device__ __forceinline__ void gbar_wait(int* bar, int e) {     // t==0 only
    const int* root = bar + e * EVSTRIDE + 128;
    while (__hip_atomic_load(root, __ATOMIC_ACQUIRE, __HIP_MEMORY_SCOPE_AGENT) < GRPS)
        __builtin_amdgcn_s_sleep(1);
}
__device__ __forceinline__ void gbar(int* bar, int e) {
    __syncthreads();
    if (threadIdx.x == 0) { gbar_arrive(bar, e); gbar_wait(bar, e); }
    __syncthreads();
}

// Persistent co-resident kernel. Exp-domain Sinkhorn on E=exp(Mr) (f16, LDS):
//   eu_r = p_r / sum_j E_rj ev_j ;  ev_j *= q_j / tot_j ;  plan = E*eu*ev.
// NO SOR (R7/R8). exp only in setup.
__global__ __launch_bounds__(NT) void ot_all(const float* __restrict__ p,
                                             const float* __restrict__ q,
                                             const float* __restrict__ C,
                                             int* bar,
                                             float* fmax_arr,
                                             float* ddel,
                                             float* ev,
                                             float* part,
                                             float* __restrict__ out) {
    extern __shared__ u16 tile[];        // [ROWS][N]: u16 quant, then f16 E in place
    const int t = threadIdx.x;
    const int b = blockIdx.x;
    const int lane = t & 63;
    const int wave = t >> 6;             // 0..15
    const int gid = b * NT + t;
    const int r0 = b * ROWS;             // owned rows
    const int c0 = b * 16;               // owned cols (phase B)
    const int j0 = t * 4;                // per-thread col slice

    __shared__ float sred[4][16];
    __shared__ float wbc[4];
    __shared__ float s2[16][16];
    __shared__ float dm[16];
    __shared__ float pp[ROWS], qq[16], eu[ROWS];
    __shared__ float sMown, sMaxC, sM;

    // ---------------- phase 0: ev-init + own-rows max; arrive early ----------------
    if (gid < N) astore(&ev[gid], 1.0f);     // published by blocks 0-3's e0 release
    {
        const float4* Crow = (const float4*)(C + (size_t)r0 * N);
        float m = 0.f;
        for (int i = t; i < ROWS * N / 4; i += NT) {
            float4 c = Crow[i];
            m = fmaxf(m, fmaxf(fmaxf(c.x, c.y), fmaxf(c.z, c.w)));
        }
#pragma unroll
        for (int off = 32; off; off >>= 1) m = fmaxf(m, __shfl_down(m, off));
        if (lane == 0) dm[wave] = m;
        __syncthreads();
        if (t == 0) {
            m = dm[0];
#pragma unroll
            for (int i = 1; i < 16; ++i) m = fmaxf(m, dm[i]);
            sMown = m;
            astore(&fmax_arr[b], m);         // ordered by the acq_rel arrive below
            gbar_arrive(bar, 0);
        }
        __syncthreads();                     // sMown visible block-wide
    }

    // ---------------- phase 1: u16-quantize own rows w/ LOCAL max (overlaps e0) ----------------
    {
        const float qmul = 65535.0f / sMown; // finer grid than global-max quant
        const float4* Crow = (const float4*)(C + (size_t)r0 * N);
        uint2* T2 = (uint2*)tile;
        for (int i = t; i < ROWS * N / 4; i += NT) {
            float4 a = Crow[i];
            uint2 o;
            o.x = min(65535u, __float2uint_rn(a.x * qmul)) | (min(65535u, __float2uint_rn(a.y * qmul)) << 16);
            o.y = min(65535u, __float2uint_rn(a.z * qmul)) | (min(65535u, __float2uint_rn(a.w * qmul)) << 16);
            T2[i] = o;
        }
        if (t < ROWS) {
            pp[t] = p[r0 + t];
            qq[t] = q[c0 + t];
        }
    }
    __syncthreads();
    if (t == 0) gbar_wait(bar, 0);
    __syncthreads();
    if (wave == 0) {                         // reduce global max from 256 slots
        float d = fmaxf(fmaxf(aload(&fmax_arr[lane]), aload(&fmax_arr[64 + lane])),
                        fmaxf(aload(&fmax_arr[128 + lane]), aload(&fmax_arr[192 + lane])));
#pragma unroll
        for (int off = 32; off; off >>= 1) d = fmaxf(d, __shfl_down(d, off));
        if (lane == 0) sMaxC = d;
    }
    __syncthreads();

    // ---------------- convert tile in place: u16 q -> f16 E = exp2(q * nd2) ----------------
    {
        const float nd2 = -(20.0f / 65535.0f) * (sMown / sMaxC) * LOG2E;
        uint2* T2 = (uint2*)tile;
        for (int i = t; i < ROWS * N / 4; i += NT) {
            uint2 a = T2[i];
            float e0 = fexp2((float)(a.x & 0xffffu) * nd2);
            float e1 = fexp2((float)(a.x >> 16) * nd2);
            float e2 = fexp2((float)(a.y & 0xffffu) * nd2);
            float e3 = fexp2((float)(a.y >> 16) * nd2);
            a.x = pkh2(e0, e1);
            a.y = pkh2(e2, e3);
            T2[i] = a;
        }
    }
    __syncthreads();
    float evreg = 1.0f;    // own col's ev (valid for t<16; only this block writes it)

    // ---------------- Sinkhorn iterations (exp domain, plain Gauss-Seidel) ----------------
    for (int it = 0; it < NITER; ++it) {
        // ---- phase A: S_r = sum_j E_rj*ev_j; eu_r = p_r/S_r; colpart_j += E*ev*eu ----
        float evv[4];
#pragma unroll
        for (int k = 0; k < 4; ++k) evv[k] = aload(&ev[j0 + k]);
        float ca[4] = {0.f, 0.f, 0.f, 0.f};

        for (int ch = 0; ch < 4; ++ch) {
            const int rl = ch * 4;
            float tq[4][4], sp[4];
#pragma unroll
            for (int r = 0; r < 4; ++r) {
                uint2 a = *(const uint2*)(tile + (size_t)(rl + r) * N + j0);
                float2 x0 = uph2(a.x);
                float2 x1 = uph2(a.y);
                float t0 = x0.x * evv[0];
                float t1 = x0.y * evv[1];
                float t2 = x1.x * evv[2];
                float t3 = x1.y * evv[3];
                tq[r][0] = t0; tq[r][1] = t1; tq[r][2] = t2; tq[r][3] = t3;
                sp[r] = (t0 + t1) + (t2 + t3);
            }
#pragma unroll
            for (int r = 0; r < 4; ++r) {
                float s = sp[r];
#pragma unroll
                for (int off = 32; off; off >>= 1) s += __shfl_down(s, off);
                if (lane == 0) sred[r][wave] = s;
            }
            __syncthreads();
            if (wave < 4) {  // wave w finalizes local row rl+w
                float s = (lane < 16) ? sred[wave][lane] : 0.f;
                s += __shfl_down(s, 8);
                s += __shfl_down(s, 4);
                s += __shfl_down(s, 2);
                s += __shfl_down(s, 1);
                if (lane == 0) {
                    const float w = pp[rl + wave] / s;   // eu_r
                    wbc[wave] = w;
                    eu[rl + wave] = w;                   // kept for final
                }
            }
            __syncthreads();
#pragma unroll
            for (int r = 0; r < 4; ++r) {
                const float w = wbc[r];
#pragma unroll
                for (int k = 0; k < 4; ++k) ca[k] = fmaf(tq[r][k], w, ca[k]);
            }
        }
#pragma unroll
        for (int k = 0; k < 4; ++k) astore(&part[(size_t)b * N + j0 + k], ca[k]);
        gbar(bar, 1 + 2 * it);

        // ---- phase B: tot_j = sum_b part[b][j]; ev_j *= q_j/tot; d = |q/tot - 1| ----
        {
            const int cl = t & 15;       // col-local
            const int ch = t >> 4;       // 0..63 part-row group
            const int c = c0 + cl;
            float s = 0.f;
#pragma unroll
            for (int k = 0; k < 4; ++k) s += aload(&part[(size_t)(ch + 64 * k) * N + c]);
            s += __shfl_down(s, 16);
            s += __shfl_down(s, 32);
            if (lane < 16) s2[cl][wave] = s;
            __syncthreads();
            if (t < 16) {
                float tot = 0.f;
#pragma unroll
                for (int w = 0; w < 16; ++w) tot += s2[t][w];
                const float rr = qq[t] / tot;
                const float evn = evreg * rr;
                astore(&ev[c0 + t], evn);
                evreg = evn;
                float d = fabsf(rr - 1.0f);
                d = fmaxf(d, __shfl_down(d, 8));
                d = fmaxf(d, __shfl_down(d, 4));
                d = fmaxf(d, __shfl_down(d, 2));
                d = fmaxf(d, __shfl_down(d, 1));
                if (t == 0) astore(&ddel[it * NB + b], d);   // own slot, relaxed
            }
        }
        gbar(bar, 2 + 2 * it);

        // ---- wave0 reduces published ddel -> grid-uniform m ----
        if (wave == 0) {
            const float* dd = ddel + it * NB;
            float d = fmaxf(fmaxf(aload(dd + lane), aload(dd + 64 + lane)),
                            fmaxf(aload(dd + 128 + lane), aload(dd + 192 + lane)));
#pragma unroll
            for (int off = 32; off; off >>= 1) d = fmaxf(d, __shfl_down(d, off));
            if (lane == 0) sM = d;
        }
        __syncthreads();
        if (sM < TOL) break;    // identical data/order everywhere -> uniform
    }

    // ---------------- final: out = E * eu_r * ev_j (no exp) ----------------
    {
        float ev4[4];
#pragma unroll
        for (int k = 0; k < 4; ++k) ev4[k] = aload(&ev[j0 + k]);
#pragma unroll 4
        for (int r = 0; r < ROWS; ++r) {
            const float g = eu[r];
            uint2 a = *(const uint2*)(tile + (size_t)r * N + j0);
            float2 x0 = uph2(a.x);
            float2 x1 = uph2(a.y);
            float4 o;
            o.x = x0.x * (g * ev4[0]);
            o.y = x0.y * (g * ev4[1]);
            o.z = x1.x * (g * ev4[2]);
            o.w = x1.y * (g * ev4[3]);
            *(float4*)(out + (size_t)(r0 + r) * N + j0) = o;
        }
    }
}

extern "C" void kernel_launch(void* const* d_in, const int* in_sizes, int n_in,
                              void* d_out, int out_size, void* d_ws, size_t ws_size,
                              hipStream_t stream) {
    const float* p = (const float*)d_in[0];
    const float* q = (const float*)d_in[1];
    const float* C = (const float*)d_in[2];
    float* out = (float*)d_out;

    char* base = (char*)d_ws;
    int* bar = (int*)base;                              // (1+2*NITER)*EVSTRIDE ints ~ 113 KB, memset 0
    float* fmax_arr = (float*)(base + 120 * 1024);      // NB floats (barrier-guarded)
    float* ddel = (float*)(base + 124 * 1024);          // NITER*NB floats (barrier-guarded)
    float* ev = (float*)(base + 228 * 1024);            // N floats (init'd in-kernel)
    float* part = (float*)(base + 256 * 1024);          // NB x N f32 = 4 MB (barrier-guarded)

    (void)hipMemsetAsync(d_ws, 0, (size_t)(1 + 2 * NITER) * EVSTRIDE * sizeof(int), stream);

    (void)hipFuncSetAttribute((const void*)ot_all, hipFuncAttributeMaxDynamicSharedMemorySize, TILE_BYTES);

    void* args[] = {(void*)&p, (void*)&q, (void*)&C, (void*)&bar,
                    (void*)&fmax_arr, (void*)&ddel, (void*)&ev, (void*)&part, (void*)&out};
    (void)hipLaunchCooperativeKernel((void*)ot_all, dim3(NB), dim3(NT), args, TILE_BYTES, stream);
}

// Round 16
// 211.215 us; speedup vs baseline: 1.2638x; 1.1179x over previous
//
#include <hip/hip_runtime.h>

#define N 4096
#define NITER 100
#define LOG2E 1.44269504088896340736f
#define TOL 3e-4f        // R9/R10-proven: exit here == 100-iter reference (absmax 2.98e-8)
#define NB 256
#define NT 1024
#define ROWS 16                      // rows owned per block, u16-quantized in LDS
#define TILE_BYTES (ROWS * N * 2)    // 128 KiB
#define GRPS 8
#define BPG 32                       // blocks per group
#define EVSTRIDE 144                 // ints per event: 8 grp counters @16-int spacing + root @128

typedef unsigned short u16;

// Cross-XCD-coherent scalar accessors (per-XCD L2 NOT coherent). 32-bit ONLY
// (R7: 64-bit agent atomics regressed). Ordering via the barrier's ACQ_REL
// arrival chain + acquire root spin (R12-proven). f16 tile reverted (R15:
// −2 µs VALU but +2 µs/iter on the latency path).
__device__ __forceinline__ float aload(const float* p) {
    return __hip_atomic_load(p, __ATOMIC_RELAXED, __HIP_MEMORY_SCOPE_AGENT);
}
__device__ __forceinline__ void astore(float* p, float x) {
    __hip_atomic_store(p, x, __ATOMIC_RELAXED, __HIP_MEMORY_SCOPE_AGENT);
}

__device__ __forceinline__ float fexp2(float x) {
#if __has_builtin(__builtin_amdgcn_exp2f)
    return __builtin_amdgcn_exp2f(x);        // raw v_exp_f32
#else
    return __expf(x * 0.6931471805599453f);  // exp(x*ln2) == 2^x
#endif
}

// Hierarchical one-shot barrier (R12-proven, ~4.5us/event). Arrival: acq_rel
// fetch_add on own group's line (8 lines in parallel); group-last acq_rel-adds
// the root. Wait: spin ONE address (root) with acquire + s_sleep (R11/R14
// lessons: no multi-address polling, no aggregator two-hop).
__device__ __forceinline__ void gbar_arrive(int* bar, int e) {   // t==0 only
    int* base = bar + e * EVSTRIDE;
    const int g = (int)(blockIdx.x >> 5);
    int r = __hip_atomic_fetch_add(base + g * 16, 1, __ATOMIC_ACQ_REL, __HIP_MEMORY_SCOPE_AGENT);
    if (r == BPG - 1)
        __hip_atomic_fetch_add(base + 128, 1, __ATOMIC_ACQ_REL, __HIP_MEMORY_SCOPE_AGENT);
}
__device__ __forceinline__ void gbar_wait(int* bar, int e) {     // t==0 only
    const int* root = bar + e * EVSTRIDE + 128;
    while (__hip_atomic_load(root, __ATOMIC_ACQUIRE, __HIP_MEMORY_SCOPE_AGENT) < GRPS)
        __builtin_amdgcn_s_sleep(1);
}
__device__ __forceinline__ void gbar(int* bar, int e) {
    __syncthreads();
    if (threadIdx.x == 0) { gbar_arrive(bar, e); gbar_wait(bar, e); }
    __syncthreads();
}

// Persistent co-resident kernel (R12 structure verbatim; one change: v is
// WARM-STARTED at v0 = log q, which captures the dominant variation of the
// fixpoint potential v* = log q - log(colsum) [colsum varies only ~±5%].
// Same fixpoint (scale-equivariant); expected K ~ 7-9 instead of 12.
__global__ __launch_bounds__(NT) void ot_all(const float* __restrict__ p,
                                             const float* __restrict__ q,
                                             const float* __restrict__ C,
                                             int* bar,
                                             float* fmax_arr,
                                             float* ddel,
                                             float* v,
                                             float* part,
                                             float* __restrict__ out) {
    extern __shared__ u16 tile[];        // [ROWS][N] = 128 KiB
    const int t = threadIdx.x;
    const int b = blockIdx.x;
    const int lane = t & 63;
    const int wave = t >> 6;             // 0..15
    const int gid = b * NT + t;
    const int r0 = b * ROWS;             // owned rows (phase A / final)
    const int c0 = b * 16;               // owned cols (phase B)
    const int j0 = t * 4;                // per-thread col slice

    __shared__ float sred[4][16];
    __shared__ float wbc[4];
    __shared__ float s2[16][16];
    __shared__ float dm[16];
    __shared__ float lp[ROWS], pp[ROWS], lq[16], su[ROWS];
    __shared__ float sMown, sMaxC, sM;

    // ---------------- phase 0: warm v-init + own-rows max; arrive early ----------------
    if (gid < N) astore(&v[gid], __logf(q[gid]));   // v0 = log q (published by e0 release)
    {
        const float4* Crow = (const float4*)(C + (size_t)r0 * N);
        float m = 0.f;
        for (int i = t; i < ROWS * N / 4; i += NT) {
            float4 c = Crow[i];
            m = fmaxf(m, fmaxf(fmaxf(c.x, c.y), fmaxf(c.z, c.w)));
        }
#pragma unroll
        for (int off = 32; off; off >>= 1) m = fmaxf(m, __shfl_down(m, off));
        if (lane == 0) dm[wave] = m;
        __syncthreads();
        if (t == 0) {
            m = dm[0];
#pragma unroll
            for (int i = 1; i < 16; ++i) m = fmaxf(m, dm[i]);
            sMown = m;
            astore(&fmax_arr[b], m);         // ordered by the acq_rel arrive below
            gbar_arrive(bar, 0);
        }
        __syncthreads();                     // sMown visible block-wide
    }

    // ---------------- phase 1: quantize own rows w/ LOCAL max (overlaps e0) ----------------
    {
        const float qmul = 65535.0f / sMown; // finer grid than global-max quant
        const float4* Crow = (const float4*)(C + (size_t)r0 * N);
        uint2* T2 = (uint2*)tile;
        for (int i = t; i < ROWS * N / 4; i += NT) {
            float4 a = Crow[i];
            uint2 o;
            o.x = min(65535u, __float2uint_rn(a.x * qmul)) | (min(65535u, __float2uint_rn(a.y * qmul)) << 16);
            o.y = min(65535u, __float2uint_rn(a.z * qmul)) | (min(65535u, __float2uint_rn(a.w * qmul)) << 16);
            T2[i] = o;
        }
        if (t < ROWS) {
            float pv = p[r0 + t];
            pp[t] = pv;
            lp[t] = __logf(pv);
            lq[t] = __logf(q[c0 + t]);       // bitwise == v0 of the owned col
        }
    }
    __syncthreads();
    if (t == 0) gbar_wait(bar, 0);
    __syncthreads();
    if (wave == 0) {                         // reduce global max from 256 slots
        float d = fmaxf(fmaxf(aload(&fmax_arr[lane]), aload(&fmax_arr[64 + lane])),
                        fmaxf(aload(&fmax_arr[128 + lane]), aload(&fmax_arr[192 + lane])));
#pragma unroll
        for (int off = 32; off; off >>= 1) d = fmaxf(d, __shfl_down(d, off));
        if (lane == 0) sMaxC = d;
    }
    __syncthreads();
    // Mr = -(C/maxC)/0.05; C ~= q16 * m_own/65535 -> Mr ~= -q16 * ndstep (exp2 domain)
    const float ndstep = -(20.0f / 65535.0f) * (sMown / sMaxC) * LOG2E;
    float vreg = lq[t & 15];   // own col's v0 (valid for t<16; only this block writes it)

    // ---------------- Sinkhorn iterations (plain Gauss-Seidel; NO SOR: R7/R8) ----------------
    for (int it = 0; it < NITER; ++it) {
        // ---- phase A: S_r = sum_j exp(Mr+v_j); u_r = logp_r - log S_r;
        //      colpart_j += t_rj * (p_r/S_r) ----
        float vv2[4];
#pragma unroll
        for (int k = 0; k < 4; ++k) vv2[k] = aload(&v[j0 + k]) * LOG2E;
        float ca[4] = {0.f, 0.f, 0.f, 0.f};

        for (int ch = 0; ch < 4; ++ch) {
            const int rl = ch * 4;
            float tq[4][4], sp[4];
#pragma unroll
            for (int r = 0; r < 4; ++r) {
                uint2 a = *(const uint2*)(tile + (size_t)(rl + r) * N + j0);
                float e0 = fexp2(fmaf((float)(a.x & 0xffffu), ndstep, vv2[0]));
                float e1 = fexp2(fmaf((float)(a.x >> 16),     ndstep, vv2[1]));
                float e2 = fexp2(fmaf((float)(a.y & 0xffffu), ndstep, vv2[2]));
                float e3 = fexp2(fmaf((float)(a.y >> 16),     ndstep, vv2[3]));
                tq[r][0] = e0; tq[r][1] = e1; tq[r][2] = e2; tq[r][3] = e3;
                sp[r] = (e0 + e1) + (e2 + e3);
            }
#pragma unroll
            for (int r = 0; r < 4; ++r) {
                float s = sp[r];
#pragma unroll
                for (int off = 32; off; off >>= 1) s += __shfl_down(s, off);
                if (lane == 0) sred[r][wave] = s;
            }
            __syncthreads();
            if (wave < 4) {  // wave w finalizes local row rl+w
                float s = (lane < 16) ? sred[wave][lane] : 0.f;
                s += __shfl_down(s, 8);
                s += __shfl_down(s, 4);
                s += __shfl_down(s, 2);
                s += __shfl_down(s, 1);
                if (lane == 0) {
                    wbc[wave] = pp[rl + wave] / s;             // exp(u_new_r)
                    su[rl + wave] = lp[rl + wave] - __logf(s); // u_new_r (block-local)
                }
            }
            __syncthreads();
#pragma unroll
            for (int r = 0; r < 4; ++r) {
                const float w = wbc[r];
#pragma unroll
                for (int k = 0; k < 4; ++k) ca[k] = fmaf(tq[r][k], w, ca[k]);
            }
        }
#pragma unroll
        for (int k = 0; k < 4; ++k) astore(&part[(size_t)b * N + j0 + k], ca[k]);
        gbar(bar, 1 + 2 * it);

        // ---- phase B: v_j = logq_j + v_old_j - log( sum_b part[b][j] ) for 16 owned cols ----
        {
            const int cl = t & 15;       // col-local
            const int ch = t >> 4;       // 0..63 part-row group
            const int c = c0 + cl;
            float s = 0.f;
#pragma unroll
            for (int k = 0; k < 4; ++k) s += aload(&part[(size_t)(ch + 64 * k) * N + c]);
            s += __shfl_down(s, 16);
            s += __shfl_down(s, 32);
            if (lane < 16) s2[cl][wave] = s;
            __syncthreads();
            if (t < 16) {
                float tot = 0.f;
#pragma unroll
                for (int w = 0; w < 16; ++w) tot += s2[t][w];
                const float vn = lq[t] + vreg - __logf(tot);
                astore(&v[c0 + t], vn);
                float d = fabsf(vn - vreg);
                vreg = vn;
                d = fmaxf(d, __shfl_down(d, 8));
                d = fmaxf(d, __shfl_down(d, 4));
                d = fmaxf(d, __shfl_down(d, 2));
                d = fmaxf(d, __shfl_down(d, 1));
                if (t == 0) astore(&ddel[it * NB + b], d);   // own slot, relaxed
            }
        }
        gbar(bar, 2 + 2 * it);

        // ---- wave0 reduces published ddel -> grid-uniform m ----
        if (wave == 0) {
            const float* dd = ddel + it * NB;
            float d = fmaxf(fmaxf(aload(dd + lane), aload(dd + 64 + lane)),
                            fmaxf(aload(dd + 128 + lane), aload(dd + 192 + lane)));
#pragma unroll
            for (int off = 32; off; off >>= 1) d = fmaxf(d, __shfl_down(d, off));
            if (lane == 0) sM = d;
        }
        __syncthreads();
        if (sM < TOL) break;    // identical data/order everywhere -> uniform
    }

    // ---------------- final: out rows from LDS tile + su + coherent v ----------------
    {
        float vvl[4];
#pragma unroll
        for (int k = 0; k < 4; ++k) vvl[k] = aload(&v[j0 + k]) * LOG2E;
#pragma unroll 4
        for (int r = 0; r < ROWS; ++r) {
            const float uul = su[r] * LOG2E;
            uint2 a = *(const uint2*)(tile + (size_t)r * N + j0);
            float4 o;
            o.x = fexp2(fmaf((float)(a.x & 0xffffu), ndstep, uul + vvl[0]));
            o.y = fexp2(fmaf((float)(a.x >> 16),     ndstep, uul + vvl[1]));
            o.z = fexp2(fmaf((float)(a.y & 0xffffu), ndstep, uul + vvl[2]));
            o.w = fexp2(fmaf((float)(a.y >> 16),     ndstep, uul + vvl[3]));
            *(float4*)(out + (size_t)(r0 + r) * N + j0) = o;
        }
    }
}

extern "C" void kernel_launch(void* const* d_in, const int* in_sizes, int n_in,
                              void* d_out, int out_size, void* d_ws, size_t ws_size,
                              hipStream_t stream) {
    const float* p = (const float*)d_in[0];
    const float* q = (const float*)d_in[1];
    const float* C = (const float*)d_in[2];
    float* out = (float*)d_out;

    char* base = (char*)d_ws;
    int* bar = (int*)base;                              // (1+2*NITER)*EVSTRIDE ints ~ 113 KB, memset 0
    float* fmax_arr = (float*)(base + 120 * 1024);      // NB floats (barrier-guarded)
    float* ddel = (float*)(base + 124 * 1024);          // NITER*NB floats (barrier-guarded)
    float* v = (float*)(base + 228 * 1024);             // N floats (init'd in-kernel)
    float* part = (float*)(base + 256 * 1024);          // NB x N f32 = 4 MB (barrier-guarded)

    (void)hipMemsetAsync(d_ws, 0, (size_t)(1 + 2 * NITER) * EVSTRIDE * sizeof(int), stream);

    (void)hipFuncSetAttribute((const void*)ot_all, hipFuncAttributeMaxDynamicSharedMemorySize, TILE_BYTES);

    void* args[] = {(void*)&p, (void*)&q, (void*)&C, (void*)&bar,
                    (void*)&fmax_arr, (void*)&ddel, (void*)&v, (void*)&part, (void*)&out};
    (void)hipLaunchCooperativeKernel((void*)ot_all, dim3(NB), dim3(NT), args, TILE_BYTES, stream);
}